// Round 6
// baseline (10269.202 us; speedup 1.0000x reference)
//
#include <hip/hip_runtime.h>
#include <hip/hip_bf16.h>

// Problem constants
#define BB   128
#define SS   512
#define IND  512
#define HID  1024
#define NBLK 256   // 4 row-quarters (mi) x 64 column-groups (jg)
#define NCTR 32    // barrier stripes (one 64B LLC line each)

#define WHH_LD (HID + 8)   // LDS row pad
#define WIH_LD (IND + 8)

typedef __attribute__((ext_vector_type(8))) short s8v;   // 8 x bf16
typedef __attribute__((ext_vector_type(4))) float f4v;   // MFMA accumulator
typedef unsigned long long u64;
typedef unsigned int u32;

__device__ __forceinline__ short f2bf(float f) {
    union { float f; u32 u; } v; v.f = f;
    u32 u = v.u + 0x7FFFu + ((v.u >> 16) & 1u);          // RNE
    return (short)(u >> 16);
}

// h ping-pong layout (bf16, per buffer 256 KB):
//   [wg=8][kk=32][kg=4][row 16][8 shorts]
// Element (b, j) at byte:
//   (b/16)*32768 + (j>>5)*1024 + ((j>>3)&3)*256 + (b%16)*16 + (j&7)*2

__global__ void __launch_bounds__(128, 1)
gru_persistent(const float* __restrict__ X,     // [B,S,IND]
               const float* __restrict__ Wih,   // [3H, IND]
               const float* __restrict__ Whh,   // [3H, HID]
               const float* __restrict__ bih,   // [3H]
               const float* __restrict__ bhh,   // [3H]
               float* __restrict__ out,         // [B,S,H] ++ [B,H]
               short* __restrict__ bufA,        // ws scratch (even t)
               short* __restrict__ bufB,        // d_out tail region (odd t)
               u64*   __restrict__ ctr)         // 32 stripes + epoch word
{
    __shared__ __align__(16) short whh_lds[48 * WHH_LD];
    __shared__ __align__(16) short wih_lds[48 * WIH_LD];

    const int tid  = threadIdx.x;
    const int wave = tid >> 6;      // 0..1
    const int lane = tid & 63;
    const int blk  = blockIdx.x;
    const int mi   = blk >> 6;      // 0..3 row quarter
    const int jg   = blk & 63;      // column group

    u64* epoch = ctr + NCTR * 8;    // separate 64B line

    // ---- stage weight slices to LDS as bf16 (once) ----
    for (int idx = tid; idx < 48 * (HID / 4); idx += 128) {
        int s = idx / (HID / 4), k4 = idx % (HID / 4);
        int grow = (s >> 4) * HID + jg * 16 + (s & 15);
        float4 v = *(const float4*)(Whh + (size_t)grow * HID + k4 * 4);
        short* d = &whh_lds[s * WHH_LD + k4 * 4];
        d[0] = f2bf(v.x); d[1] = f2bf(v.y); d[2] = f2bf(v.z); d[3] = f2bf(v.w);
    }
    for (int idx = tid; idx < 48 * (IND / 4); idx += 128) {
        int s = idx / (IND / 4), k4 = idx % (IND / 4);
        int grow = (s >> 4) * HID + jg * 16 + (s & 15);
        float4 v = *(const float4*)(Wih + (size_t)grow * IND + k4 * 4);
        short* d = &wih_lds[s * WIH_LD + k4 * 4];
        d[0] = f2bf(v.x); d[1] = f2bf(v.y); d[2] = f2bf(v.z); d[3] = f2bf(v.w);
    }

    const int n  = lane & 15;
    const int kg = lane >> 4;
    const int j  = jg * 16 + n;
    const float bir = bih[j], biz = bih[HID + j], bin_ = bih[2 * HID + j];
    const float bhr = bhh[j], bhz = bhh[HID + j], bhn  = bhh[2 * HID + j];

    const int rowbase = mi * 32 + wave * 16;
    const int wg      = mi * 2 + wave;          // row-group = rowbase/16

    // writer byte offset (even lanes store packed u32 covering cols j, j+1)
    const int wkk = j >> 5, wkg = (j >> 3) & 3;
    const u32 wbyte = (u32)wg * 32768u + (u32)wkk * 1024u + (u32)wkg * 256u
                    + (u32)kg * 64u + ((u32)(n & 7) << 1);

    float hkeep[4] = {0.f, 0.f, 0.f, 0.f};      // this lane's own h elements

    __syncthreads();

    for (int t = 0; t < SS; ++t) {
        f4v acc_r  = {0.f,0.f,0.f,0.f};
        f4v acc_z  = {0.f,0.f,0.f,0.f};
        f4v acc_in = {0.f,0.f,0.f,0.f};
        f4v acc_hn = {0.f,0.f,0.f,0.f};
        s8v areg[32];

        // ---- h_{t-1} LLC loads issued FIRST: latency hides under gi ----
        if (t > 0) {
            const short* hr = (t & 1) ? bufA : bufB;          // h_{t-1}
            const u64* hb = (const u64*)hr + (size_t)wg * 4096 + lane * 2;
            #pragma unroll
            for (int kk = 0; kk < 32; ++kk) {
                u64 lo = __hip_atomic_load(hb + kk * 128,
                                           __ATOMIC_RELAXED, __HIP_MEMORY_SCOPE_AGENT);
                u64 hi = __hip_atomic_load(hb + kk * 128 + 1,
                                           __ATOMIC_RELAXED, __HIP_MEMORY_SCOPE_AGENT);
                union { u64 q[2]; s8v v; } u; u.q[0] = lo; u.q[1] = hi;
                areg[kk] = u.v;
            }
        }

        // ---- gi: X[:,t,:] @ Wih_slice^T (K=512), normal cached loads ----
        {
            const float* xrow = X + ((size_t)(rowbase + n) * SS + t) * IND;
            #pragma unroll 4
            for (int kk = 0; kk < IND / 32; ++kk) {
                const int k0 = kk * 32 + kg * 8;
                const float4* px = (const float4*)(xrow + k0);
                float4 x0 = px[0], x1 = px[1];
                s8v a;
                a[0]=f2bf(x0.x); a[1]=f2bf(x0.y); a[2]=f2bf(x0.z); a[3]=f2bf(x0.w);
                a[4]=f2bf(x1.x); a[5]=f2bf(x1.y); a[6]=f2bf(x1.z); a[7]=f2bf(x1.w);
                s8v br = *(const s8v*)&wih_lds[(0 * 16 + n) * WIH_LD + k0];
                s8v bz = *(const s8v*)&wih_lds[(1 * 16 + n) * WIH_LD + k0];
                s8v bn = *(const s8v*)&wih_lds[(2 * 16 + n) * WIH_LD + k0];
                acc_r  = __builtin_amdgcn_mfma_f32_16x16x32_bf16(a, br, acc_r,  0,0,0);
                acc_z  = __builtin_amdgcn_mfma_f32_16x16x32_bf16(a, bz, acc_z,  0,0,0);
                acc_in = __builtin_amdgcn_mfma_f32_16x16x32_bf16(a, bn, acc_in, 0,0,0);
            }
        }

        // ---- gh: h_{t-1} @ Whh_slice^T (K=1024), A-frags already in regs ----
        if (t > 0) {
            #pragma unroll
            for (int kk = 0; kk < 32; ++kk) {
                const int k0 = kk * 32 + kg * 8;
                s8v br = *(const s8v*)&whh_lds[(0 * 16 + n) * WHH_LD + k0];
                s8v bz = *(const s8v*)&whh_lds[(1 * 16 + n) * WHH_LD + k0];
                s8v bn = *(const s8v*)&whh_lds[(2 * 16 + n) * WHH_LD + k0];
                acc_r  = __builtin_amdgcn_mfma_f32_16x16x32_bf16(areg[kk], br, acc_r,  0,0,0);
                acc_z  = __builtin_amdgcn_mfma_f32_16x16x32_bf16(areg[kk], bz, acc_z,  0,0,0);
                acc_hn = __builtin_amdgcn_mfma_f32_16x16x32_bf16(areg[kk], bn, acc_hn, 0,0,0);
            }
        }

        // ---- gates + state update; h kept in regs ----
        short* hw = (t & 1) ? bufB : bufA;                    // h_t
        u32 packv[4];
        #pragma unroll
        for (int r = 0; r < 4; ++r) {
            const int b = rowbase + kg * 4 + r;
            float gr = acc_r[r] + bir + bhr;
            float gz = acc_z[r] + biz + bhz;
            float rr = 1.f / (1.f + __expf(-gr));
            float zz = 1.f / (1.f + __expf(-gz));
            float hn = acc_hn[r] + bhn;                       // t=0: == bhn
            float na = acc_in[r] + bin_ + rr * hn;
            float e2 = __expf(2.f * na);
            float nn = (e2 - 1.f) / (e2 + 1.f);
            float hnew = (1.f - zz) * nn + zz * hkeep[r];
            hkeep[r] = hnew;
            out[(size_t)b * (SS * HID) + (size_t)t * HID + j] = hnew;
            if (t == SS - 1)
                out[(size_t)BB * SS * HID + (size_t)b * HID + j] = hnew;
            u32 hb16  = (u32)(unsigned short)f2bf(hnew);
            u32 other = (u32)__shfl_xor((int)hb16, 1);
            packv[r] = hb16 | (other << 16);                  // cols j (lo), j+1 (hi)
        }

        if (t < SS - 1) {
            if (!(n & 1)) {
                #pragma unroll
                for (int r = 0; r < 4; ++r)
                    __hip_atomic_store((u32*)((char*)hw + wbyte + r * 16), packv[r],
                                       __ATOMIC_RELAXED, __HIP_MEMORY_SCOPE_AGENT);
            }
            // ---- sense-broadcast grid barrier ----
            // __syncthreads drains vmcnt(0): all h stores at LLC before arrive.
            __syncthreads();
            if (tid == 0) {
                __hip_atomic_fetch_add(&ctr[(blk & 31) * 8], 1ull,
                                       __ATOMIC_RELAXED, __HIP_MEMORY_SCOPE_AGENT);
                const u64 target = (u64)NBLK * (u64)(t + 1);
                if (blk == 0) {
                    // sole stripe-poller: gathers, then broadcasts epoch
                    for (;;) {
                        u64 s = 0;
                        #pragma unroll
                        for (int i = 0; i < NCTR; ++i)
                            s += __hip_atomic_load(&ctr[i * 8], __ATOMIC_RELAXED,
                                                   __HIP_MEMORY_SCOPE_AGENT);
                        if (s >= target) break;
                        __builtin_amdgcn_s_sleep(1);
                    }
                    __hip_atomic_store(epoch, (u64)(t + 1),
                                       __ATOMIC_RELAXED, __HIP_MEMORY_SCOPE_AGENT);
                } else {
                    // read-only spin on one broadcast word (no RMW interference)
                    while (__hip_atomic_load(epoch, __ATOMIC_RELAXED,
                                             __HIP_MEMORY_SCOPE_AGENT) < (u64)(t + 1))
                        __builtin_amdgcn_s_sleep(1);
                }
            }
            __syncthreads();
        }
    }
}

extern "C" void kernel_launch(void* const* d_in, const int* in_sizes, int n_in,
                              void* d_out, int out_size, void* d_ws, size_t ws_size,
                              hipStream_t stream) {
    const float* X   = (const float*)d_in[0];
    const float* Wih = (const float*)d_in[1];
    const float* Whh = (const float*)d_in[2];
    const float* bih = (const float*)d_in[3];
    const float* bhh = (const float*)d_in[4];
    float* out = (float*)d_out;

    u64*   ctr  = (u64*)d_ws;                         // 32 stripes + epoch (64B apart)
    short* bufA = (short*)((char*)d_ws + 4096);       // 256 KB (even-t h)
    // odd-t h buffer lives in the d_out h_last tail (512 KB region, only
    // validated after t=SS-1; fully overwritten with f32 h_last at t=SS-1,
    // ordered by the step-(SS-2) barrier).
    short* bufB = (short*)(out + (size_t)BB * SS * HID);

    hipMemsetAsync(d_ws, 0, 4096, stream);            // zero stripes + epoch

    void* args[] = { (void*)&X, (void*)&Wih, (void*)&Whh, (void*)&bih,
                     (void*)&bhh, (void*)&out, (void*)&bufA, (void*)&bufB,
                     (void*)&ctr };
    hipLaunchCooperativeKernel((const void*)gru_persistent,
                               dim3(NBLK), dim3(128), args, 0, stream);
}

// Round 8
// 4068.838 us; speedup vs baseline: 2.5239x; 2.5239x over previous
//
#include <hip/hip_runtime.h>
#include <hip/hip_bf16.h>

// Problem constants
#define BB   128
#define SS   512
#define IND  512
#define HID  1024
#define NBLK 256     // 4 row-quarters (mi) x 64 column-groups (jg)
#define GRPBLK 64    // blocks per mi-group (independent sub-GRU)
#define NSTRIPE 8    // stripes per group (one 64B LLC line each)

#define WHH_LD (HID + 8)   // LDS row pad
#define WIH_LD (IND + 8)

typedef __attribute__((ext_vector_type(8))) short s8v;   // 8 x bf16
typedef __attribute__((ext_vector_type(4))) float f4v;   // MFMA accumulator
typedef unsigned long long u64;
typedef unsigned int u32;

__device__ __forceinline__ short f2bf(float f) {
    union { float f; u32 u; } v; v.f = f;
    u32 u = v.u + 0x7FFFu + ((v.u >> 16) & 1u);          // RNE
    return (short)(u >> 16);
}

// h ping-pong layout (bf16):
//   bufA (ws, 256 KB):   [wg=8][kk=32][kg=4][row 16][8 shorts]
//   bufB (out tail):     group mi's slice at byte mi*131072, layout
//                        [wg&1][kk=32][kg=4][row 16][8 shorts] (64 KB/group)
//   -> bufB slice of group mi lies inside group mi's OWN h_last rows
//      [32mi, 32mi+16), so the t=SS-1 f32 h_last overwrite is group-local
//      and ordered by the group's t=SS-2 barrier. No cross-group bytes.

__global__ void __launch_bounds__(128, 1)
gru_persistent(const float* __restrict__ X,     // [B,S,IND]
               const float* __restrict__ Wih,   // [3H, IND]
               const float* __restrict__ Whh,   // [3H, HID]
               const float* __restrict__ bih,   // [3H]
               const float* __restrict__ bhh,   // [3H]
               float* __restrict__ out,         // [B,S,H] ++ [B,H]
               short* __restrict__ bufA,        // ws scratch (even t)
               short* __restrict__ bufB,        // d_out tail region (odd t)
               u64*   __restrict__ ctr)         // 4 groups x 8 stripes, 64B apart
{
    __shared__ __align__(16) short whh_lds[48 * WHH_LD];
    __shared__ __align__(16) short wih_lds[48 * WIH_LD];

    const int tid  = threadIdx.x;
    const int wave = tid >> 6;      // 0..1
    const int lane = tid & 63;
    const int blk  = blockIdx.x;
    const int mi   = blk >> 6;      // 0..3 row quarter == barrier group
    const int jg   = blk & 63;      // column group

    // ---- stage weight slices to LDS as bf16 (once) ----
    for (int idx = tid; idx < 48 * (HID / 4); idx += 128) {
        int s = idx / (HID / 4), k4 = idx % (HID / 4);
        int grow = (s >> 4) * HID + jg * 16 + (s & 15);
        float4 v = *(const float4*)(Whh + (size_t)grow * HID + k4 * 4);
        short* d = &whh_lds[s * WHH_LD + k4 * 4];
        d[0] = f2bf(v.x); d[1] = f2bf(v.y); d[2] = f2bf(v.z); d[3] = f2bf(v.w);
    }
    for (int idx = tid; idx < 48 * (IND / 4); idx += 128) {
        int s = idx / (IND / 4), k4 = idx % (IND / 4);
        int grow = (s >> 4) * HID + jg * 16 + (s & 15);
        float4 v = *(const float4*)(Wih + (size_t)grow * IND + k4 * 4);
        short* d = &wih_lds[s * WIH_LD + k4 * 4];
        d[0] = f2bf(v.x); d[1] = f2bf(v.y); d[2] = f2bf(v.z); d[3] = f2bf(v.w);
    }

    const int n  = lane & 15;
    const int kg = lane >> 4;
    const int j  = jg * 16 + n;
    const float bir = bih[j], biz = bih[HID + j], bin_ = bih[2 * HID + j];
    const float bhr = bhh[j], bhz = bhh[HID + j], bhn  = bhh[2 * HID + j];

    const int rowbase = mi * 32 + wave * 16;
    const int wg      = mi * 2 + wave;          // row-group = rowbase/16

    // writer byte offsets (even lanes store packed u32 covering cols j, j+1)
    const int wkk = j >> 5, wkg = (j >> 3) & 3;
    const u32 rest   = (u32)wkk * 1024u + (u32)wkg * 256u
                     + (u32)kg * 64u + ((u32)(n & 7) << 1);
    const u32 wbyteA = (u32)wg * 32768u + rest;
    const u32 wbyteB = (u32)mi * 131072u + (u32)(wg & 1) * 32768u + rest;

    // reader u64 offsets (lane-contiguous 16B per lane)
    const u64* hbA = (const u64*)bufA + (size_t)wg * 4096 + lane * 2;
    const u64* hbB = (const u64*)bufB + (size_t)mi * 16384
                   + (size_t)(wg & 1) * 4096 + lane * 2;

    float hkeep[4] = {0.f, 0.f, 0.f, 0.f};      // this lane's own h elements

    __syncthreads();

    for (int t = 0; t < SS; ++t) {
        f4v acc_r  = {0.f,0.f,0.f,0.f};
        f4v acc_z  = {0.f,0.f,0.f,0.f};
        f4v acc_in = {0.f,0.f,0.f,0.f};
        f4v acc_hn = {0.f,0.f,0.f,0.f};

        // ---- gi: X[:,t,:] @ Wih_slice^T (K=512), normal cached loads ----
        {
            const float* xrow = X + ((size_t)(rowbase + n) * SS + t) * IND;
            #pragma unroll 4
            for (int kk = 0; kk < IND / 32; ++kk) {
                const int k0 = kk * 32 + kg * 8;
                const float4* px = (const float4*)(xrow + k0);
                float4 x0 = px[0], x1 = px[1];
                s8v a;
                a[0]=f2bf(x0.x); a[1]=f2bf(x0.y); a[2]=f2bf(x0.z); a[3]=f2bf(x0.w);
                a[4]=f2bf(x1.x); a[5]=f2bf(x1.y); a[6]=f2bf(x1.z); a[7]=f2bf(x1.w);
                s8v br = *(const s8v*)&wih_lds[(0 * 16 + n) * WIH_LD + k0];
                s8v bz = *(const s8v*)&wih_lds[(1 * 16 + n) * WIH_LD + k0];
                s8v bn = *(const s8v*)&wih_lds[(2 * 16 + n) * WIH_LD + k0];
                acc_r  = __builtin_amdgcn_mfma_f32_16x16x32_bf16(a, br, acc_r,  0,0,0);
                acc_z  = __builtin_amdgcn_mfma_f32_16x16x32_bf16(a, bz, acc_z,  0,0,0);
                acc_in = __builtin_amdgcn_mfma_f32_16x16x32_bf16(a, bn, acc_in, 0,0,0);
            }
        }

        // ---- gh: h_{t-1} @ Whh_slice^T (K=1024) via LLC-coherent loads ----
        if (t > 0) {
            const u64* hb = (t & 1) ? hbA : hbB;              // h_{t-1}
            s8v areg[32];
            #pragma unroll
            for (int kk = 0; kk < 32; ++kk) {
                u64 lo = __hip_atomic_load(hb + kk * 128,
                                           __ATOMIC_RELAXED, __HIP_MEMORY_SCOPE_AGENT);
                u64 hi = __hip_atomic_load(hb + kk * 128 + 1,
                                           __ATOMIC_RELAXED, __HIP_MEMORY_SCOPE_AGENT);
                union { u64 q[2]; s8v v; } u; u.q[0] = lo; u.q[1] = hi;
                areg[kk] = u.v;
            }
            #pragma unroll
            for (int kk = 0; kk < 32; ++kk) {
                const int k0 = kk * 32 + kg * 8;
                s8v br = *(const s8v*)&whh_lds[(0 * 16 + n) * WHH_LD + k0];
                s8v bz = *(const s8v*)&whh_lds[(1 * 16 + n) * WHH_LD + k0];
                s8v bn = *(const s8v*)&whh_lds[(2 * 16 + n) * WHH_LD + k0];
                acc_r  = __builtin_amdgcn_mfma_f32_16x16x32_bf16(areg[kk], br, acc_r,  0,0,0);
                acc_z  = __builtin_amdgcn_mfma_f32_16x16x32_bf16(areg[kk], bz, acc_z,  0,0,0);
                acc_hn = __builtin_amdgcn_mfma_f32_16x16x32_bf16(areg[kk], bn, acc_hn, 0,0,0);
            }
        }

        // ---- gates + state update; h kept in regs ----
        u32 packv[4];
        #pragma unroll
        for (int r = 0; r < 4; ++r) {
            const int b = rowbase + kg * 4 + r;
            float gr = acc_r[r] + bir + bhr;
            float gz = acc_z[r] + biz + bhz;
            float rr = 1.f / (1.f + __expf(-gr));
            float zz = 1.f / (1.f + __expf(-gz));
            float hn = acc_hn[r] + bhn;                       // t=0: == bhn
            float na = acc_in[r] + bin_ + rr * hn;
            float e2 = __expf(2.f * na);
            float nn = (e2 - 1.f) / (e2 + 1.f);
            float hnew = (1.f - zz) * nn + zz * hkeep[r];
            hkeep[r] = hnew;
            out[(size_t)b * (SS * HID) + (size_t)t * HID + j] = hnew;
            if (t == SS - 1)
                out[(size_t)BB * SS * HID + (size_t)b * HID + j] = hnew;
            u32 hb16  = (u32)(unsigned short)f2bf(hnew);
            u32 other = (u32)__shfl_xor((int)hb16, 1);
            packv[r] = hb16 | (other << 16);                  // cols j (lo), j+1 (hi)
        }

        if (t < SS - 1) {
            if (!(n & 1)) {
                char* base = (t & 1) ? ((char*)bufB + wbyteB) : ((char*)bufA + wbyteA);
                #pragma unroll
                for (int r = 0; r < 4; ++r)
                    __hip_atomic_store((u32*)(base + r * 16), packv[r],
                                       __ATOMIC_RELAXED, __HIP_MEMORY_SCOPE_AGENT);
            }
            // ---- per-mi-group barrier (64 blocks), striped fan-in + distributed poll.
            // __syncthreads drains vmcnt(0) -> all h stores at LLC before arrive.
            __syncthreads();
            if (tid == 0) {
                __hip_atomic_fetch_add(&ctr[(mi * NSTRIPE + (blk & 7)) * 8], 1ull,
                                       __ATOMIC_RELAXED, __HIP_MEMORY_SCOPE_AGENT);
                const u64 target = (u64)GRPBLK * (u64)(t + 1);
                for (;;) {
                    u64 s = 0;
                    #pragma unroll
                    for (int i = 0; i < NSTRIPE; ++i)
                        s += __hip_atomic_load(&ctr[(mi * NSTRIPE + i) * 8],
                                               __ATOMIC_RELAXED,
                                               __HIP_MEMORY_SCOPE_AGENT);
                    if (s >= target) break;
                    __builtin_amdgcn_s_sleep(1);
                }
            }
            __syncthreads();
        }
    }
}

extern "C" void kernel_launch(void* const* d_in, const int* in_sizes, int n_in,
                              void* d_out, int out_size, void* d_ws, size_t ws_size,
                              hipStream_t stream) {
    const float* X   = (const float*)d_in[0];
    const float* Wih = (const float*)d_in[1];
    const float* Whh = (const float*)d_in[2];
    const float* bih = (const float*)d_in[3];
    const float* bhh = (const float*)d_in[4];
    float* out = (float*)d_out;

    u64*   ctr  = (u64*)d_ws;                         // 4x8 stripes on 64B stride = 2 KB
    short* bufA = (short*)((char*)d_ws + 4096);       // 256 KB (even-t h)
    // odd-t h: per-group 64 KB slices inside each group's OWN h_last rows
    // (tail bytes [mi*128KB, mi*128KB+64KB)); overwritten group-locally at
    // t=SS-1 after the group's t=SS-2 barrier.
    short* bufB = (short*)(out + (size_t)BB * SS * HID);

    hipMemsetAsync(d_ws, 0, 4096, stream);            // zero barrier stripes

    void* args[] = { (void*)&X, (void*)&Wih, (void*)&Whh, (void*)&bih,
                     (void*)&bhh, (void*)&out, (void*)&bufA, (void*)&bufB,
                     (void*)&ctr };
    hipLaunchCooperativeKernel((const void*)gru_persistent,
                               dim3(NBLK), dim3(128), args, 0, stream);
}